// Round 10
// baseline (864.844 us; speedup 1.0000x reference)
//
#include <hip/hip_runtime.h>
#include <hip/hip_bf16.h>

// GraphSAGE decoder, 4 layers. CSR-gather aggregation, bf16 feature tables,
// bf16-MFMA GEMMs with fp32 accumulate, LN fused into GEMM epilogues
// (in-register partial reduction; no C round-trip through LDS).
// CSR fill bucketed (2 passes, 3.2MB L2-resident write window).

#define EPS 1e-5f

typedef unsigned short u16;
typedef short bf16x8_t __attribute__((ext_vector_type(8)));
typedef float f32x4_t __attribute__((ext_vector_type(4)));

__device__ inline unsigned int bfpack(float a, float b) {
    unsigned int ua = __builtin_bit_cast(unsigned int, a);
    unsigned int ub = __builtin_bit_cast(unsigned int, b);
    ua += 0x7fffu + ((ua >> 16) & 1u);
    ub += 0x7fffu + ((ub >> 16) & 1u);
    return (ua >> 16) | (ub & 0xffff0000u);
}

__device__ inline u16 bfr(float a) {
    unsigned int u = __builtin_bit_cast(unsigned int, a);
    u += 0x7fffu + ((u >> 16) & 1u);
    return (u16)(u >> 16);
}

__device__ inline float bf2f(u16 v) {
    unsigned int u = ((unsigned int)v) << 16;
    return __builtin_bit_cast(float, u);
}

__device__ inline float bflo(unsigned int q) { return __builtin_bit_cast(float, q << 16); }
__device__ inline float bfhi(unsigned int q) { return __builtin_bit_cast(float, q & 0xffff0000u); }

#define ACC8(A, Q)                                         \
    A[0] += bflo(Q.x); A[1] += bfhi(Q.x);                  \
    A[2] += bflo(Q.y); A[3] += bfhi(Q.y);                  \
    A[4] += bflo(Q.z); A[5] += bfhi(Q.z);                  \
    A[6] += bflo(Q.w); A[7] += bfhi(Q.w);

// ---------------- zero fill ----------------
__global__ __launch_bounds__(256) void zero_f4(float4* __restrict__ p, int n4) {
    int i = blockIdx.x * 256 + threadIdx.x;
    if (i < n4) p[i] = make_float4(0.f, 0.f, 0.f, 0.f);
}

// ---------------- fp32 -> bf16 cast ----------------
__global__ __launch_bounds__(256) void cast_bf16(const float* __restrict__ x,
                                                 u16* __restrict__ y, int n4) {
    int i = blockIdx.x * 256 + threadIdx.x;
    if (i >= n4) return;
    float4 v = ((const float4*)x)[i];
    ((uint2*)y)[i] = make_uint2(bfpack(v.x, v.y), bfpack(v.z, v.w));
}

// ---------------- all 6 weight transposes in one launch ----------------
struct WtJobs {
    const float* W[6];
    u16* WT[6];
    int K[6], N[6];
};
__global__ __launch_bounds__(256) void transpose_cast6(WtJobs jobs) {
    int j = blockIdx.y;
    int idx = blockIdx.x * 256 + threadIdx.x;
    int K = jobs.K[j], Nn = jobs.N[j];
    if (idx >= K * Nn) return;
    int k = idx / Nn, n = idx - k * Nn;
    jobs.WT[j][(long)n * K + k] = bfr(jobs.W[j][idx]);
}

// ---------------- CSR build ----------------
__global__ __launch_bounds__(256) void count_deg(const int* __restrict__ dst,
                                                 int* __restrict__ deg, int E) {
    int e = blockIdx.x * 256 + threadIdx.x;
    if (e < E) atomicAdd(&deg[dst[e]], 1);
}

__global__ __launch_bounds__(256) void partial_sums(const int* __restrict__ deg,
                                                    int* __restrict__ partials, int N) {
    __shared__ int lds[4];
    int tid = threadIdx.x;
    int base = blockIdx.x * 1024 + tid * 4;
    int s = 0;
    if (base + 3 < N) {
        int4 v = *(const int4*)(deg + base);
        s = v.x + v.y + v.z + v.w;
    } else {
        for (int i = 0; i < 4; ++i)
            if (base + i < N) s += deg[base + i];
    }
#pragma unroll
    for (int m = 32; m >= 1; m >>= 1) s += __shfl_xor(s, m);
    if ((tid & 63) == 0) lds[tid >> 6] = s;
    __syncthreads();
    if (tid == 0) partials[blockIdx.x] = lds[0] + lds[1] + lds[2] + lds[3];
}

__global__ __launch_bounds__(256) void scan_partials(int* __restrict__ partials, int nb) {
    __shared__ int lds[256];
    int tid = threadIdx.x;
    int v = (tid < nb) ? partials[tid] : 0;
    lds[tid] = v;
    __syncthreads();
    for (int off = 1; off < 256; off <<= 1) {
        int t = (tid >= off) ? lds[tid - off] : 0;
        __syncthreads();
        lds[tid] += t;
        __syncthreads();
    }
    if (tid < nb) partials[tid] = lds[tid] - v;
}

__global__ __launch_bounds__(256) void write_rowptr(const int* __restrict__ deg,
                                                    const int* __restrict__ partials,
                                                    int* __restrict__ rowptr,
                                                    int* __restrict__ cursor,
                                                    float* __restrict__ inv, int N, int E) {
    __shared__ int lds[256];
    int tid = threadIdx.x;
    int base = blockIdx.x * 1024 + tid * 4;
    int d[4];
    int s = 0;
#pragma unroll
    for (int i = 0; i < 4; ++i) {
        d[i] = (base + i < N) ? deg[base + i] : 0;
        s += d[i];
    }
    lds[tid] = s;
    __syncthreads();
    for (int off = 1; off < 256; off <<= 1) {
        int t = (tid >= off) ? lds[tid - off] : 0;
        __syncthreads();
        lds[tid] += t;
        __syncthreads();
    }
    int run = partials[blockIdx.x] + lds[tid] - s;
#pragma unroll
    for (int i = 0; i < 4; ++i) {
        int idx = base + i;
        if (idx < N) {
            rowptr[idx] = run;
            cursor[idx] = run;
            inv[idx] = 1.0f / fmaxf((float)d[i], 1.0f);
            run += d[i];
        }
    }
    if (blockIdx.x == 0 && tid == 0) rowptr[N] = E;
}

__global__ __launch_bounds__(256) void fill_csr_range(const int* __restrict__ src,
                                                      const int* __restrict__ dst,
                                                      int* __restrict__ cursor,
                                                      int* __restrict__ eidx, int E,
                                                      int lo, int bs) {
    int e = blockIdx.x * 256 + threadIdx.x;
    if (e >= E) return;
    int d = dst[e];
    if ((unsigned)(d - lo) < (unsigned)bs) {
        int p = atomicAdd(&cursor[d], 1);
        eidx[p] = src[e];
    }
}

// ---------------- gathers: 16B/lane, multi-edge in flight ----------------
__global__ __launch_bounds__(256) void gather_scale256(const u16* __restrict__ x,
                                                       const int* __restrict__ rowptr,
                                                       const int* __restrict__ eidx,
                                                       const float* __restrict__ inv,
                                                       u16* __restrict__ agg, int N) {
    int wave = threadIdx.x >> 6;
    int lane = threadIdx.x & 63;
    int half = lane >> 5;
    int sub = lane & 31;
    int row = blockIdx.x * 4 + wave;
    if (row >= N) return;
    int beg = rowptr[row], end = rowptr[row + 1];
    float a[8] = {}, b[8] = {};
    int j = beg + half;
    for (; j + 2 < end; j += 4) {
        uint4 q0 = *(const uint4*)(x + (long)eidx[j] * 256 + sub * 8);
        uint4 q1 = *(const uint4*)(x + (long)eidx[j + 2] * 256 + sub * 8);
        ACC8(a, q0);
        ACC8(b, q1);
    }
    if (j < end) {
        uint4 q = *(const uint4*)(x + (long)eidx[j] * 256 + sub * 8);
        ACC8(a, q);
    }
#pragma unroll
    for (int i = 0; i < 8; ++i) {
        a[i] += b[i];
        a[i] += __shfl_xor(a[i], 32);
    }
    if (half == 0) {
        float s = inv[row];
        uint4 o;
        o.x = bfpack(a[0] * s, a[1] * s);
        o.y = bfpack(a[2] * s, a[3] * s);
        o.z = bfpack(a[4] * s, a[5] * s);
        o.w = bfpack(a[6] * s, a[7] * s);
        *(uint4*)(agg + (long)row * 256 + sub * 8) = o;
    }
}

__global__ __launch_bounds__(256) void gather_scale128(const u16* __restrict__ x,
                                                       const int* __restrict__ rowptr,
                                                       const int* __restrict__ eidx,
                                                       const float* __restrict__ inv,
                                                       u16* __restrict__ agg, int N) {
    int wave = threadIdx.x >> 6;
    int lane = threadIdx.x & 63;
    int quarter = lane >> 4;
    int sub = lane & 15;
    int row = blockIdx.x * 4 + wave;
    if (row >= N) return;
    int beg = rowptr[row], end = rowptr[row + 1];
    float a[8] = {}, b[8] = {};
    int j = beg + quarter;
    for (; j + 4 < end; j += 8) {
        uint4 q0 = *(const uint4*)(x + (long)eidx[j] * 128 + sub * 8);
        uint4 q1 = *(const uint4*)(x + (long)eidx[j + 4] * 128 + sub * 8);
        ACC8(a, q0);
        ACC8(b, q1);
    }
    if (j < end) {
        uint4 q = *(const uint4*)(x + (long)eidx[j] * 128 + sub * 8);
        ACC8(a, q);
    }
#pragma unroll
    for (int i = 0; i < 8; ++i) {
        a[i] += b[i];
        a[i] += __shfl_xor(a[i], 16);
        a[i] += __shfl_xor(a[i], 32);
    }
    if (quarter == 0) {
        float s = inv[row];
        uint4 o;
        o.x = bfpack(a[0] * s, a[1] * s);
        o.y = bfpack(a[2] * s, a[3] * s);
        o.z = bfpack(a[4] * s, a[5] * s);
        o.w = bfpack(a[6] * s, a[7] * s);
        *(uint4*)(agg + (long)row * 128 + sub * 8) = o;
    }
}

// L3 fused: h3 = relu(LN(gather_mean(y3) + r3)), D=128.
__global__ __launch_bounds__(256) void gather_add_ln_relu128(const u16* __restrict__ y,
                                                             const int* __restrict__ rowptr,
                                                             const int* __restrict__ eidx,
                                                             const float* __restrict__ inv,
                                                             const u16* __restrict__ r,
                                                             const float* __restrict__ g,
                                                             const float* __restrict__ be,
                                                             u16* __restrict__ out, int N) {
    int wave = threadIdx.x >> 6;
    int lane = threadIdx.x & 63;
    int quarter = lane >> 4;
    int sub = lane & 15;
    int row = blockIdx.x * 4 + wave;
    if (row >= N) return;
    int beg = rowptr[row], end = rowptr[row + 1];
    float a[8] = {}, b[8] = {};
    int j = beg + quarter;
    for (; j + 4 < end; j += 8) {
        uint4 q0 = *(const uint4*)(y + (long)eidx[j] * 128 + sub * 8);
        uint4 q1 = *(const uint4*)(y + (long)eidx[j + 4] * 128 + sub * 8);
        ACC8(a, q0);
        ACC8(b, q1);
    }
    if (j < end) {
        uint4 q = *(const uint4*)(y + (long)eidx[j] * 128 + sub * 8);
        ACC8(a, q);
    }
#pragma unroll
    for (int i = 0; i < 8; ++i) {
        a[i] += b[i];
        a[i] += __shfl_xor(a[i], 16);
        a[i] += __shfl_xor(a[i], 32);
    }
    float iv = inv[row];
    uint4 rr = *(const uint4*)(r + (long)row * 128 + sub * 8);
    float v[8];
    v[0] = a[0] * iv + bflo(rr.x); v[1] = a[1] * iv + bfhi(rr.x);
    v[2] = a[2] * iv + bflo(rr.y); v[3] = a[3] * iv + bfhi(rr.y);
    v[4] = a[4] * iv + bflo(rr.z); v[5] = a[5] * iv + bfhi(rr.z);
    v[6] = a[6] * iv + bflo(rr.w); v[7] = a[7] * iv + bfhi(rr.w);
    float s = 0.f, ss = 0.f;
#pragma unroll
    for (int i = 0; i < 8; ++i) { s += v[i]; ss += v[i] * v[i]; }
#pragma unroll
    for (int m = 8; m >= 1; m >>= 1) {
        s += __shfl_xor(s, m);
        ss += __shfl_xor(ss, m);
    }
    float mean = s / 128.f;
    float var = ss / 128.f - mean * mean;
    float rs = rsqrtf(var + EPS);
    if (quarter == 0) {
        int col = sub * 8;
        float4 g0 = *(const float4*)&g[col];
        float4 g1 = *(const float4*)&g[col + 4];
        float4 e0 = *(const float4*)&be[col];
        float4 e1 = *(const float4*)&be[col + 4];
        float o0 = fmaxf((v[0] - mean) * rs * g0.x + e0.x, 0.f);
        float o1 = fmaxf((v[1] - mean) * rs * g0.y + e0.y, 0.f);
        float o2 = fmaxf((v[2] - mean) * rs * g0.z + e0.z, 0.f);
        float o3 = fmaxf((v[3] - mean) * rs * g0.w + e0.w, 0.f);
        float o4 = fmaxf((v[4] - mean) * rs * g1.x + e1.x, 0.f);
        float o5 = fmaxf((v[5] - mean) * rs * g1.y + e1.y, 0.f);
        float o6 = fmaxf((v[6] - mean) * rs * g1.z + e1.z, 0.f);
        float o7 = fmaxf((v[7] - mean) * rs * g1.w + e1.w, 0.f);
        uint4 o;
        o.x = bfpack(o0, o1);
        o.y = bfpack(o2, o3);
        o.z = bfpack(o4, o5);
        o.w = bfpack(o6, o7);
        *(uint4*)(out + (long)row * 128 + sub * 8) = o;
    }
}

// final: out = gather_sum(y)*inv + r, y bf16, out fp32
__global__ __launch_bounds__(256) void gather9_final(const u16* __restrict__ y,
                                                     const int* __restrict__ rowptr,
                                                     const int* __restrict__ eidx,
                                                     const float* __restrict__ inv,
                                                     const float* __restrict__ r,
                                                     float* __restrict__ out, int N) {
    int idx = blockIdx.x * 256 + threadIdx.x;
    int row = idx >> 4;
    int c = idx & 15;
    if (row >= N || c >= 9) return;
    int beg = rowptr[row], end = rowptr[row + 1];
    float a = 0.f;
    for (int j = beg; j < end; ++j) a += bf2f(y[(long)eidx[j] * 9 + c]);
    out[(long)row * 9 + c] = a * inv[row] + r[(long)row * 9 + c];
}

// ---------------- 128-row MFMA GEMM + in-register LN epilogue ----------------
// out = relu(LN(A1@W1 + A2@W2 + bias))*g + be. BM=128, BN=256(=Dout), BK=32.
// 4 waves: wave w covers rows (w&1)*64..+64, cols (w>>1)*128..+128.
// LN: per-row partials reduced in-register (shfl within 16-lane quad groups),
// cross-wave combine via 2KB LDS buffer. out must NOT alias A1/A2.
__global__ __launch_bounds__(256) void mfma_gemm128_ln(const u16* __restrict__ A1,
                                                       const u16* __restrict__ A2,
                                                       const u16* __restrict__ WT1,
                                                       const u16* __restrict__ WT2,
                                                       const float* __restrict__ bias,
                                                       const float* __restrict__ g,
                                                       const float* __restrict__ be,
                                                       u16* __restrict__ out, int M, int K) {
    __shared__ u16 As[128 * 40];
    __shared__ u16 Ws[256 * 40];
    __shared__ float sred[128][2];
    __shared__ float ssred[128][2];
    const int tid = threadIdx.x;
    const int bm = blockIdx.x * 128;
    const int l = tid & 63;
    const int w = tid >> 6;
    const int wr = (w & 1) * 64;
    const int wc = (w >> 1) * 128;
    const int ln15 = l & 15;
    const int quad = l >> 4;

    f32x4_t acc[4][8];
#pragma unroll
    for (int i = 0; i < 4; ++i)
#pragma unroll
        for (int j = 0; j < 8; ++j) acc[i][j] = (f32x4_t){0.f, 0.f, 0.f, 0.f};

    const int sr = tid >> 1;         // A staging row 0..127
    const int kh = (tid & 1) * 16;   // A staging k offset

    for (int pass = 0; pass < 2; ++pass) {
        const u16* A = pass ? A2 : A1;
        const u16* WT = pass ? WT2 : WT1;
        for (int k0 = 0; k0 < K; k0 += 32) {
            uint4 q0 = make_uint4(0, 0, 0, 0), q1 = make_uint4(0, 0, 0, 0);
            int gr = bm + sr;
            if (gr < M) {
                const u16* ap = A + (long)gr * K + k0 + kh;
                q0 = ((const uint4*)ap)[0];
                q1 = ((const uint4*)ap)[1];
            }
            *(uint4*)(As + sr * 40 + kh) = q0;
            *(uint4*)(As + sr * 40 + kh + 8) = q1;
            const u16* wp = WT + (long)tid * K + k0;
            *(uint4*)(Ws + tid * 40 + 0) = ((const uint4*)wp)[0];
            *(uint4*)(Ws + tid * 40 + 8) = ((const uint4*)wp)[1];
            *(uint4*)(Ws + tid * 40 + 16) = ((const uint4*)wp)[2];
            *(uint4*)(Ws + tid * 40 + 24) = ((const uint4*)wp)[3];
            __syncthreads();

            bf16x8_t a[4], b[8];
#pragma unroll
            for (int i = 0; i < 4; ++i)
                a[i] = *(const bf16x8_t*)(As + (wr + i * 16 + ln15) * 40 + quad * 8);
#pragma unroll
            for (int j = 0; j < 8; ++j)
                b[j] = *(const bf16x8_t*)(Ws + (wc + j * 16 + ln15) * 40 + quad * 8);
#pragma unroll
            for (int i = 0; i < 4; ++i)
#pragma unroll
                for (int j = 0; j < 8; ++j)
                    acc[i][j] = __builtin_amdgcn_mfma_f32_16x16x32_bf16(a[i], b[j], acc[i][j], 0, 0, 0);
            __syncthreads();
        }
    }

    // ---- bias add (LN input includes bias) ----
    float bv[8];
#pragma unroll
    for (int j = 0; j < 8; ++j) bv[j] = bias[wc + j * 16 + ln15];
#pragma unroll
    for (int i = 0; i < 4; ++i)
#pragma unroll
        for (int j = 0; j < 8; ++j)
#pragma unroll
            for (int p = 0; p < 4; ++p) acc[i][j][p] += bv[j];

    // ---- per-row partial sums over this wave's 128 cols (in-register) ----
#pragma unroll
    for (int i = 0; i < 4; ++i) {
        float s[4] = {}, ss[4] = {};
#pragma unroll
        for (int j = 0; j < 8; ++j)
#pragma unroll
            for (int p = 0; p < 4; ++p) {
                float x = acc[i][j][p];
                s[p] += x;
                ss[p] += x * x;
            }
#pragma unroll
        for (int m = 1; m <= 8; m <<= 1)
#pragma unroll
            for (int p = 0; p < 4; ++p) {
                s[p] += __shfl_xor(s[p], m);
                ss[p] += __shfl_xor(ss[p], m);
            }
        if (ln15 == 0) {
#pragma unroll
            for (int p = 0; p < 4; ++p) {
                int r = wr + i * 16 + quad * 4 + p;
                sred[r][w >> 1] = s[p];
                ssred[r][w >> 1] = ss[p];
            }
        }
    }
    __syncthreads();

    // ---- apply LN + ReLU, write out ----
    float gv[8], ev[8];
#pragma unroll
    for (int j = 0; j < 8; ++j) {
        gv[j] = g[wc + j * 16 + ln15];
        ev[j] = be[wc + j * 16 + ln15];
    }
#pragma unroll
    for (int i = 0; i < 4; ++i) {
#pragma unroll
        for (int p = 0; p < 4; ++p) {
            int r = wr + i * 16 + quad * 4 + p;
            int grow = bm + r;
            if (grow >= M) continue;
            float s = sred[r][0] + sred[r][1];
            float ss = ssred[r][0] + ssred[r][1];
            float mean = s / 256.f;
            float var = ss / 256.f - mean * mean;
            float rs = rsqrtf(var + EPS);
#pragma unroll
            for (int j = 0; j < 8; ++j) {
                float y = (acc[i][j][p] - mean) * rs * gv[j] + ev[j];
                out[(long)grow * 256 + wc + j * 16 + ln15] = bfr(fmaxf(y, 0.f));
            }
        }
    }
}

// ---------------- L3 dual GEMM: ya = A@WTa, yb = A@WTb + bias ----------------
__global__ __launch_bounds__(256) void mfma_gemm_dual(const u16* __restrict__ A,
                                                      const u16* __restrict__ WTa,
                                                      const u16* __restrict__ WTb,
                                                      const float* __restrict__ biasb,
                                                      u16* __restrict__ outa,
                                                      u16* __restrict__ outb, int M, int K) {
    __shared__ u16 As[128 * 40];
    __shared__ u16 Ws[128 * 40];
    const u16* WT = blockIdx.y ? WTb : WTa;
    u16* out = blockIdx.y ? outb : outa;
    const float* bias = blockIdx.y ? biasb : nullptr;
    const int tid = threadIdx.x;
    const int bm = blockIdx.x * 128;
    const int l = tid & 63;
    const int w = tid >> 6;
    const int wr = (w & 1) * 64;
    const int wc = (w >> 1) * 64;
    const int ln15 = l & 15;
    const int quad = l >> 4;

    f32x4_t acc[4][4];
#pragma unroll
    for (int i = 0; i < 4; ++i)
#pragma unroll
        for (int j = 0; j < 4; ++j) acc[i][j] = (f32x4_t){0.f, 0.f, 0.f, 0.f};

    const int sr = tid >> 1;
    const int kh = (tid & 1) * 16;

    for (int k0 = 0; k0 < K; k0 += 32) {
        uint4 q0 = make_uint4(0, 0, 0, 0), q1 = make_uint4(0, 0, 0, 0);
        int gr = bm + sr;
        if (gr < M) {
            const u16* ap = A + (long)gr * K + k0 + kh;
            q0 = ((const uint4*)ap)[0];
            q1 = ((const uint4*)ap)[1];
        }
        *(uint4*)(As + sr * 40 + kh) = q0;
        *(uint4*)(As + sr * 40 + kh + 8) = q1;
        const u16* wp = WT + (long)sr * K + k0 + kh;
        *(uint4*)(Ws + sr * 40 + kh) = ((const uint4*)wp)[0];
        *(uint4*)(Ws + sr * 40 + kh + 8) = ((const uint4*)wp)[1];
        __syncthreads();

        bf16x8_t a[4], b[4];
#pragma unroll
        for (int i = 0; i < 4; ++i)
            a[i] = *(const bf16x8_t*)(As + (wr + i * 16 + ln15) * 40 + quad * 8);
#pragma unroll
        for (int j = 0; j < 4; ++j)
            b[j] = *(const bf16x8_t*)(Ws + (wc + j * 16 + ln15) * 40 + quad * 8);
#pragma unroll
        for (int i = 0; i < 4; ++i)
#pragma unroll
            for (int j = 0; j < 4; ++j)
                acc[i][j] = __builtin_amdgcn_mfma_f32_16x16x32_bf16(a[i], b[j], acc[i][j], 0, 0, 0);
        __syncthreads();
    }

#pragma unroll
    for (int j = 0; j < 4; ++j) {
        int col = wc + j * 16 + ln15;
        float bv = bias ? bias[col] : 0.f;
#pragma unroll
        for (int i = 0; i < 4; ++i) {
            int row0 = bm + wr + i * 16 + quad * 4;
            f32x4_t c = acc[i][j];
#pragma unroll
            for (int p = 0; p < 4; ++p) {
                int row = row0 + p;
                if (row < M) out[(long)row * 128 + col] = bfr(c[p] + bv);
            }
        }
    }
}

// ---------------- layer 4 small GEMM ----------------
__global__ __launch_bounds__(320) void gemm4_bf(const u16* __restrict__ x,
                                                const float* __restrict__ wm,
                                                const float* __restrict__ wrt,
                                                const float* __restrict__ b,
                                                u16* __restrict__ y, float* __restrict__ r,
                                                int M) {
    __shared__ float xs[16][132];
    __shared__ float ws[128][20];
    int tid = threadIdx.x;
    int m0 = blockIdx.x * 16;
    for (int idx = tid; idx < 16 * 128; idx += 320) {
        int rr = idx >> 7, kk = idx & 127;
        int gm = m0 + rr;
        xs[rr][kk] = (gm < M) ? bf2f(x[(long)gm * 128 + kk]) : 0.f;
    }
    for (int idx = tid; idx < 128 * 18; idx += 320) {
        int kk = idx / 18, cc = idx % 18;
        ws[kk][cc] = (cc < 9) ? wm[kk * 9 + cc] : wrt[kk * 9 + cc - 9];
    }
    __syncthreads();
    if (tid < 288) {
        int rr = tid / 18, cc = tid % 18;
        float acc = 0.f;
#pragma unroll 8
        for (int kk = 0; kk < 128; ++kk) acc += xs[rr][kk] * ws[kk][cc];
        int gm = m0 + rr;
        if (gm < M) {
            if (cc < 9) y[(long)gm * 9 + cc] = bfr(acc);
            else r[(long)gm * 9 + cc - 9] = acc + b[cc - 9];
        }
    }
}

static inline int cdiv(long a, long b) { return (int)((a + b - 1) / b); }

extern "C" void kernel_launch(void* const* d_in, const int* in_sizes, int n_in,
                              void* d_out, int out_size, void* d_ws, size_t ws_size,
                              hipStream_t stream) {
    const int N = in_sizes[0] / 128;
    const int E = in_sizes[1] / 2;

    const float* z = (const float*)d_in[0];
    const int* ei = (const int*)d_in[1];
    const int* src = ei;
    const int* dstp = ei + E;
    const float* wm1 = (const float*)d_in[2];
    const float* wr1 = (const float*)d_in[3];
    const float* b1 = (const float*)d_in[4];
    const float* g1 = (const float*)d_in[5];
    const float* be1 = (const float*)d_in[6];
    const float* wm2 = (const float*)d_in[7];
    const float* wr2 = (const float*)d_in[8];
    const float* b2 = (const float*)d_in[9];
    const float* g2 = (const float*)d_in[10];
    const float* be2 = (const float*)d_in[11];
    const float* wm3 = (const float*)d_in[12];
    const float* wr3 = (const float*)d_in[13];
    const float* b3 = (const float*)d_in[14];
    const float* g3 = (const float*)d_in[15];
    const float* be3 = (const float*)d_in[16];
    const float* wm4 = (const float*)d_in[17];
    const float* wr4 = (const float*)d_in[18];
    const float* b4 = (const float*)d_in[19];
    float* out = (float*)d_out;

    // ws layout (u16 regions then metadata):
    u16* aggh2 = (u16*)d_ws;                     // N*256
    u16* h1b = aggh2 + (size_t)N * 256;          // N*256
    u16* zb = h1b + (size_t)N * 256;             // N*128
    u16* agg1 = zb + (size_t)N * 128;            // N*128 (zb..agg1 = contiguous N*256)
    float* inv = (float*)(agg1 + (size_t)N * 128);
    int* deg = (int*)(inv + N);
    int* rowptr = deg + N + 4;
    int* cursor = rowptr + N + 4;
    int* partials = cursor + N + 4;
    int* eidx = partials + 256;
    u16* wt1m = (u16*)(eidx + E);
    u16* wt1r = wt1m + 256 * 128;
    u16* wt2m = wt1r + 256 * 128;
    u16* wt2r = wt2m + 256 * 256;
    u16* wt3m = wt2r + 256 * 256;
    u16* wt3r = wt3m + 128 * 256;

    // liveness-checked aliases:
    u16* h2 = zb;                      // N*256 over zb+agg1 (both dead after GEMM1)
    u16* y3b = aggh2;                  // aggh2 dead after GEMM2
    u16* r3b = aggh2 + (size_t)N * 128;
    u16* h3b = h1b;                    // h1b dead after GEMM2
    u16* y4 = aggh2;                   // y3b/r3b dead after L3 gather
    float* r4 = (float*)(aggh2 + (size_t)N * 16);

    const int nscan = cdiv(N, 1024);

    // ---- prep ----
    cast_bf16<<<cdiv((long)N * 32, 256), 256, 0, stream>>>(z, zb, N * 32);
    zero_f4<<<cdiv(N, 1024), 256, 0, stream>>>((float4*)deg, cdiv(N, 4));
    count_deg<<<cdiv(E, 256), 256, 0, stream>>>(dstp, deg, E);
    partial_sums<<<nscan, 256, 0, stream>>>(deg, partials, N);
    scan_partials<<<1, 256, 0, stream>>>(partials, nscan);
    write_rowptr<<<nscan, 256, 0, stream>>>(deg, partials, rowptr, cursor, inv, N, E);
    {
        const int P = 2;  // 3.2MB eidx window per pass <= 4MiB per-XCD L2
        int bs = cdiv(N, P);
        for (int b = 0; b < P; ++b)
            fill_csr_range<<<cdiv(E, 256), 256, 0, stream>>>(src, dstp, cursor, eidx, E,
                                                             b * bs, bs);
    }
    {
        WtJobs jobs;
        jobs.W[0] = wm1; jobs.WT[0] = wt1m; jobs.K[0] = 128; jobs.N[0] = 256;
        jobs.W[1] = wr1; jobs.WT[1] = wt1r; jobs.K[1] = 128; jobs.N[1] = 256;
        jobs.W[2] = wm2; jobs.WT[2] = wt2m; jobs.K[2] = 256; jobs.N[2] = 256;
        jobs.W[3] = wr2; jobs.WT[3] = wt2r; jobs.K[3] = 256; jobs.N[3] = 256;
        jobs.W[4] = wm3; jobs.WT[4] = wt3m; jobs.K[4] = 256; jobs.N[4] = 128;
        jobs.W[5] = wr3; jobs.WT[5] = wt3r; jobs.K[5] = 256; jobs.N[5] = 128;
        dim3 g(256, 6);
        transpose_cast6<<<g, 256, 0, stream>>>(jobs);
    }

    // ---- layer 1: gather z -> agg1; GEMM+LN -> h1b ----
    gather_scale128<<<cdiv(N, 4), 256, 0, stream>>>(zb, rowptr, eidx, inv, agg1, N);
    mfma_gemm128_ln<<<cdiv(N, 128), 256, 0, stream>>>(agg1, zb, wt1m, wt1r, b1, g1, be1,
                                                      h1b, N, 128);

    // ---- layer 2: gather h1 -> aggh2; GEMM+LN -> h2 (zb region; no aliasing) ----
    gather_scale256<<<cdiv(N, 4), 256, 0, stream>>>(h1b, rowptr, eidx, inv, aggh2, N);
    mfma_gemm128_ln<<<cdiv(N, 128), 256, 0, stream>>>(aggh2, h1b, wt2m, wt2r, b2, g2, be2,
                                                      h2, N, 256);

    // ---- layer 3: dual GEMM (reads h2) -> y3b/r3b; fused gather+add+LN ----
    {
        dim3 g(cdiv(N, 128), 2);
        mfma_gemm_dual<<<g, 256, 0, stream>>>(h2, wt3m, wt3r, b3, y3b, r3b, N, 256);
    }
    gather_add_ln_relu128<<<cdiv(N, 4), 256, 0, stream>>>(y3b, rowptr, eidx, inv, r3b, g3,
                                                          be3, h3b, N);

    // ---- layer 4 ----
    gemm4_bf<<<cdiv(N, 16), 320, 0, stream>>>(h3b, wm4, wr4, b4, y4, r4, N);
    gather9_final<<<cdiv((long)N * 16, 256), 256, 0, stream>>>(y4, rowptr, eidx, inv, r4, out, N);
}

// Round 11
// 844.429 us; speedup vs baseline: 1.0242x; 1.0242x over previous
//
#include <hip/hip_runtime.h>
#include <hip/hip_bf16.h>

// GraphSAGE decoder, 4 layers. CSR-gather aggregation, bf16 feature tables,
// bf16-MFMA GEMMs with fp32 accumulate, LN fused into GEMM epilogues.
// R10 post-mortem: BM=128 GEMM tile regressed (8% occupancy, 782-block grid
// -> tail waste). BM=64 (1563 blocks, ~6 block-waves) restored; fill stays
// at 2 bucketed passes (3.2MB L2-resident eidx write window).

#define EPS 1e-5f

typedef unsigned short u16;
typedef short bf16x8_t __attribute__((ext_vector_type(8)));
typedef float f32x4_t __attribute__((ext_vector_type(4)));

__device__ inline unsigned int bfpack(float a, float b) {
    unsigned int ua = __builtin_bit_cast(unsigned int, a);
    unsigned int ub = __builtin_bit_cast(unsigned int, b);
    ua += 0x7fffu + ((ua >> 16) & 1u);
    ub += 0x7fffu + ((ub >> 16) & 1u);
    return (ua >> 16) | (ub & 0xffff0000u);
}

__device__ inline u16 bfr(float a) {
    unsigned int u = __builtin_bit_cast(unsigned int, a);
    u += 0x7fffu + ((u >> 16) & 1u);
    return (u16)(u >> 16);
}

__device__ inline float bf2f(u16 v) {
    unsigned int u = ((unsigned int)v) << 16;
    return __builtin_bit_cast(float, u);
}

__device__ inline float bflo(unsigned int q) { return __builtin_bit_cast(float, q << 16); }
__device__ inline float bfhi(unsigned int q) { return __builtin_bit_cast(float, q & 0xffff0000u); }

#define ACC8(A, Q)                                         \
    A[0] += bflo(Q.x); A[1] += bfhi(Q.x);                  \
    A[2] += bflo(Q.y); A[3] += bfhi(Q.y);                  \
    A[4] += bflo(Q.z); A[5] += bfhi(Q.z);                  \
    A[6] += bflo(Q.w); A[7] += bfhi(Q.w);

// ---------------- zero fill ----------------
__global__ __launch_bounds__(256) void zero_f4(float4* __restrict__ p, int n4) {
    int i = blockIdx.x * 256 + threadIdx.x;
    if (i < n4) p[i] = make_float4(0.f, 0.f, 0.f, 0.f);
}

// ---------------- fp32 -> bf16 cast ----------------
__global__ __launch_bounds__(256) void cast_bf16(const float* __restrict__ x,
                                                 u16* __restrict__ y, int n4) {
    int i = blockIdx.x * 256 + threadIdx.x;
    if (i >= n4) return;
    float4 v = ((const float4*)x)[i];
    ((uint2*)y)[i] = make_uint2(bfpack(v.x, v.y), bfpack(v.z, v.w));
}

// ---------------- all 6 weight transposes in one launch ----------------
struct WtJobs {
    const float* W[6];
    u16* WT[6];
    int K[6], N[6];
};
__global__ __launch_bounds__(256) void transpose_cast6(WtJobs jobs) {
    int j = blockIdx.y;
    int idx = blockIdx.x * 256 + threadIdx.x;
    int K = jobs.K[j], Nn = jobs.N[j];
    if (idx >= K * Nn) return;
    int k = idx / Nn, n = idx - k * Nn;
    jobs.WT[j][(long)n * K + k] = bfr(jobs.W[j][idx]);
}

// ---------------- CSR build ----------------
__global__ __launch_bounds__(256) void count_deg(const int* __restrict__ dst,
                                                 int* __restrict__ deg, int E) {
    int e = blockIdx.x * 256 + threadIdx.x;
    if (e < E) atomicAdd(&deg[dst[e]], 1);
}

__global__ __launch_bounds__(256) void partial_sums(const int* __restrict__ deg,
                                                    int* __restrict__ partials, int N) {
    __shared__ int lds[4];
    int tid = threadIdx.x;
    int base = blockIdx.x * 1024 + tid * 4;
    int s = 0;
    if (base + 3 < N) {
        int4 v = *(const int4*)(deg + base);
        s = v.x + v.y + v.z + v.w;
    } else {
        for (int i = 0; i < 4; ++i)
            if (base + i < N) s += deg[base + i];
    }
#pragma unroll
    for (int m = 32; m >= 1; m >>= 1) s += __shfl_xor(s, m);
    if ((tid & 63) == 0) lds[tid >> 6] = s;
    __syncthreads();
    if (tid == 0) partials[blockIdx.x] = lds[0] + lds[1] + lds[2] + lds[3];
}

__global__ __launch_bounds__(256) void scan_partials(int* __restrict__ partials, int nb) {
    __shared__ int lds[256];
    int tid = threadIdx.x;
    int v = (tid < nb) ? partials[tid] : 0;
    lds[tid] = v;
    __syncthreads();
    for (int off = 1; off < 256; off <<= 1) {
        int t = (tid >= off) ? lds[tid - off] : 0;
        __syncthreads();
        lds[tid] += t;
        __syncthreads();
    }
    if (tid < nb) partials[tid] = lds[tid] - v;
}

__global__ __launch_bounds__(256) void write_rowptr(const int* __restrict__ deg,
                                                    const int* __restrict__ partials,
                                                    int* __restrict__ rowptr,
                                                    int* __restrict__ cursor,
                                                    float* __restrict__ inv, int N, int E) {
    __shared__ int lds[256];
    int tid = threadIdx.x;
    int base = blockIdx.x * 1024 + tid * 4;
    int d[4];
    int s = 0;
#pragma unroll
    for (int i = 0; i < 4; ++i) {
        d[i] = (base + i < N) ? deg[base + i] : 0;
        s += d[i];
    }
    lds[tid] = s;
    __syncthreads();
    for (int off = 1; off < 256; off <<= 1) {
        int t = (tid >= off) ? lds[tid - off] : 0;
        __syncthreads();
        lds[tid] += t;
        __syncthreads();
    }
    int run = partials[blockIdx.x] + lds[tid] - s;
#pragma unroll
    for (int i = 0; i < 4; ++i) {
        int idx = base + i;
        if (idx < N) {
            rowptr[idx] = run;
            cursor[idx] = run;
            inv[idx] = 1.0f / fmaxf((float)d[i], 1.0f);
            run += d[i];
        }
    }
    if (blockIdx.x == 0 && tid == 0) rowptr[N] = E;
}

__global__ __launch_bounds__(256) void fill_csr_range(const int* __restrict__ src,
                                                      const int* __restrict__ dst,
                                                      int* __restrict__ cursor,
                                                      int* __restrict__ eidx, int E,
                                                      int lo, int bs) {
    int e = blockIdx.x * 256 + threadIdx.x;
    if (e >= E) return;
    int d = dst[e];
    if ((unsigned)(d - lo) < (unsigned)bs) {
        int p = atomicAdd(&cursor[d], 1);
        eidx[p] = src[e];
    }
}

// ---------------- gathers: 16B/lane, multi-edge in flight ----------------
__global__ __launch_bounds__(256) void gather_scale256(const u16* __restrict__ x,
                                                       const int* __restrict__ rowptr,
                                                       const int* __restrict__ eidx,
                                                       const float* __restrict__ inv,
                                                       u16* __restrict__ agg, int N) {
    int wave = threadIdx.x >> 6;
    int lane = threadIdx.x & 63;
    int half = lane >> 5;
    int sub = lane & 31;
    int row = blockIdx.x * 4 + wave;
    if (row >= N) return;
    int beg = rowptr[row], end = rowptr[row + 1];
    float a[8] = {}, b[8] = {};
    int j = beg + half;
    for (; j + 2 < end; j += 4) {
        uint4 q0 = *(const uint4*)(x + (long)eidx[j] * 256 + sub * 8);
        uint4 q1 = *(const uint4*)(x + (long)eidx[j + 2] * 256 + sub * 8);
        ACC8(a, q0);
        ACC8(b, q1);
    }
    if (j < end) {
        uint4 q = *(const uint4*)(x + (long)eidx[j] * 256 + sub * 8);
        ACC8(a, q);
    }
#pragma unroll
    for (int i = 0; i < 8; ++i) {
        a[i] += b[i];
        a[i] += __shfl_xor(a[i], 32);
    }
    if (half == 0) {
        float s = inv[row];
        uint4 o;
        o.x = bfpack(a[0] * s, a[1] * s);
        o.y = bfpack(a[2] * s, a[3] * s);
        o.z = bfpack(a[4] * s, a[5] * s);
        o.w = bfpack(a[6] * s, a[7] * s);
        *(uint4*)(agg + (long)row * 256 + sub * 8) = o;
    }
}

__global__ __launch_bounds__(256) void gather_scale128(const u16* __restrict__ x,
                                                       const int* __restrict__ rowptr,
                                                       const int* __restrict__ eidx,
                                                       const float* __restrict__ inv,
                                                       u16* __restrict__ agg, int N) {
    int wave = threadIdx.x >> 6;
    int lane = threadIdx.x & 63;
    int quarter = lane >> 4;
    int sub = lane & 15;
    int row = blockIdx.x * 4 + wave;
    if (row >= N) return;
    int beg = rowptr[row], end = rowptr[row + 1];
    float a[8] = {}, b[8] = {};
    int j = beg + quarter;
    for (; j + 4 < end; j += 8) {
        uint4 q0 = *(const uint4*)(x + (long)eidx[j] * 128 + sub * 8);
        uint4 q1 = *(const uint4*)(x + (long)eidx[j + 4] * 128 + sub * 8);
        ACC8(a, q0);
        ACC8(b, q1);
    }
    if (j < end) {
        uint4 q = *(const uint4*)(x + (long)eidx[j] * 128 + sub * 8);
        ACC8(a, q);
    }
#pragma unroll
    for (int i = 0; i < 8; ++i) {
        a[i] += b[i];
        a[i] += __shfl_xor(a[i], 16);
        a[i] += __shfl_xor(a[i], 32);
    }
    if (quarter == 0) {
        float s = inv[row];
        uint4 o;
        o.x = bfpack(a[0] * s, a[1] * s);
        o.y = bfpack(a[2] * s, a[3] * s);
        o.z = bfpack(a[4] * s, a[5] * s);
        o.w = bfpack(a[6] * s, a[7] * s);
        *(uint4*)(agg + (long)row * 128 + sub * 8) = o;
    }
}

// L3 fused: h3 = relu(LN(gather_mean(y3) + r3)), D=128.
__global__ __launch_bounds__(256) void gather_add_ln_relu128(const u16* __restrict__ y,
                                                             const int* __restrict__ rowptr,
                                                             const int* __restrict__ eidx,
                                                             const float* __restrict__ inv,
                                                             const u16* __restrict__ r,
                                                             const float* __restrict__ g,
                                                             const float* __restrict__ be,
                                                             u16* __restrict__ out, int N) {
    int wave = threadIdx.x >> 6;
    int lane = threadIdx.x & 63;
    int quarter = lane >> 4;
    int sub = lane & 15;
    int row = blockIdx.x * 4 + wave;
    if (row >= N) return;
    int beg = rowptr[row], end = rowptr[row + 1];
    float a[8] = {}, b[8] = {};
    int j = beg + quarter;
    for (; j + 4 < end; j += 8) {
        uint4 q0 = *(const uint4*)(y + (long)eidx[j] * 128 + sub * 8);
        uint4 q1 = *(const uint4*)(y + (long)eidx[j + 4] * 128 + sub * 8);
        ACC8(a, q0);
        ACC8(b, q1);
    }
    if (j < end) {
        uint4 q = *(const uint4*)(y + (long)eidx[j] * 128 + sub * 8);
        ACC8(a, q);
    }
#pragma unroll
    for (int i = 0; i < 8; ++i) {
        a[i] += b[i];
        a[i] += __shfl_xor(a[i], 16);
        a[i] += __shfl_xor(a[i], 32);
    }
    float iv = inv[row];
    uint4 rr = *(const uint4*)(r + (long)row * 128 + sub * 8);
    float v[8];
    v[0] = a[0] * iv + bflo(rr.x); v[1] = a[1] * iv + bfhi(rr.x);
    v[2] = a[2] * iv + bflo(rr.y); v[3] = a[3] * iv + bfhi(rr.y);
    v[4] = a[4] * iv + bflo(rr.z); v[5] = a[5] * iv + bfhi(rr.z);
    v[6] = a[6] * iv + bflo(rr.w); v[7] = a[7] * iv + bfhi(rr.w);
    float s = 0.f, ss = 0.f;
#pragma unroll
    for (int i = 0; i < 8; ++i) { s += v[i]; ss += v[i] * v[i]; }
#pragma unroll
    for (int m = 8; m >= 1; m >>= 1) {
        s += __shfl_xor(s, m);
        ss += __shfl_xor(ss, m);
    }
    float mean = s / 128.f;
    float var = ss / 128.f - mean * mean;
    float rs = rsqrtf(var + EPS);
    if (quarter == 0) {
        int col = sub * 8;
        float4 g0 = *(const float4*)&g[col];
        float4 g1 = *(const float4*)&g[col + 4];
        float4 e0 = *(const float4*)&be[col];
        float4 e1 = *(const float4*)&be[col + 4];
        float o0 = fmaxf((v[0] - mean) * rs * g0.x + e0.x, 0.f);
        float o1 = fmaxf((v[1] - mean) * rs * g0.y + e0.y, 0.f);
        float o2 = fmaxf((v[2] - mean) * rs * g0.z + e0.z, 0.f);
        float o3 = fmaxf((v[3] - mean) * rs * g0.w + e0.w, 0.f);
        float o4 = fmaxf((v[4] - mean) * rs * g1.x + e1.x, 0.f);
        float o5 = fmaxf((v[5] - mean) * rs * g1.y + e1.y, 0.f);
        float o6 = fmaxf((v[6] - mean) * rs * g1.z + e1.z, 0.f);
        float o7 = fmaxf((v[7] - mean) * rs * g1.w + e1.w, 0.f);
        uint4 o;
        o.x = bfpack(o0, o1);
        o.y = bfpack(o2, o3);
        o.z = bfpack(o4, o5);
        o.w = bfpack(o6, o7);
        *(uint4*)(out + (long)row * 128 + sub * 8) = o;
    }
}

// final: out = gather_sum(y)*inv + r, y bf16, out fp32
__global__ __launch_bounds__(256) void gather9_final(const u16* __restrict__ y,
                                                     const int* __restrict__ rowptr,
                                                     const int* __restrict__ eidx,
                                                     const float* __restrict__ inv,
                                                     const float* __restrict__ r,
                                                     float* __restrict__ out, int N) {
    int idx = blockIdx.x * 256 + threadIdx.x;
    int row = idx >> 4;
    int c = idx & 15;
    if (row >= N || c >= 9) return;
    int beg = rowptr[row], end = rowptr[row + 1];
    float a = 0.f;
    for (int j = beg; j < end; ++j) a += bf2f(y[(long)eidx[j] * 9 + c]);
    out[(long)row * 9 + c] = a * inv[row] + r[(long)row * 9 + c];
}

// ---------------- wide MFMA GEMM + fused bias+LN+ReLU epilogue ----------------
// out = relu(LN(A1@W1 + A2@W2 + bias))*g + be. BM=64, BN=256(=Dout), BK=32.
// out MAY alias A1 (each block owns rows [bm,bm+64) end-to-end).
__global__ __launch_bounds__(256) void mfma_gemm_wide_ln(const u16* A1,
                                                         const u16* __restrict__ A2,
                                                         const u16* __restrict__ WT1,
                                                         const u16* __restrict__ WT2,
                                                         const float* __restrict__ bias,
                                                         const float* __restrict__ g,
                                                         const float* __restrict__ be,
                                                         u16* out, int M, int K) {
    __shared__ __align__(16) u16 smem[64 * 260];
    u16* As = smem;
    u16* Ws = smem + 64 * 40;
    const int tid = threadIdx.x;
    const int bm = blockIdx.x * 64;
    const int l = tid & 63;
    const int w = tid >> 6;
    const int wr = (w & 1) * 32;
    const int wc = (w >> 1) * 128;
    const int ln15 = l & 15;
    const int quad = l >> 4;

    f32x4_t acc[2][8];
#pragma unroll
    for (int i = 0; i < 2; ++i)
#pragma unroll
        for (int j = 0; j < 8; ++j) acc[i][j] = (f32x4_t){0.f, 0.f, 0.f, 0.f};

    const int ar = tid >> 2;
    const int akh = (tid & 3) * 8;

    for (int pass = 0; pass < 2; ++pass) {
        const u16* A = pass ? A2 : A1;
        const u16* WT = pass ? WT2 : WT1;
        for (int k0 = 0; k0 < K; k0 += 32) {
            uint4 q0 = make_uint4(0, 0, 0, 0);
            int gr = bm + ar;
            if (gr < M) q0 = *(const uint4*)(A + (long)gr * K + k0 + akh);
            *(uint4*)(As + ar * 40 + akh) = q0;
            const u16* wp = WT + (long)tid * K + k0;
            *(uint4*)(Ws + tid * 40 + 0) = ((const uint4*)wp)[0];
            *(uint4*)(Ws + tid * 40 + 8) = ((const uint4*)wp)[1];
            *(uint4*)(Ws + tid * 40 + 16) = ((const uint4*)wp)[2];
            *(uint4*)(Ws + tid * 40 + 24) = ((const uint4*)wp)[3];
            __syncthreads();

            bf16x8_t a[2], b[8];
#pragma unroll
            for (int i = 0; i < 2; ++i)
                a[i] = *(const bf16x8_t*)(As + (wr + i * 16 + ln15) * 40 + quad * 8);
#pragma unroll
            for (int j = 0; j < 8; ++j)
                b[j] = *(const bf16x8_t*)(Ws + (wc + j * 16 + ln15) * 40 + quad * 8);
#pragma unroll
            for (int i = 0; i < 2; ++i)
#pragma unroll
                for (int j = 0; j < 8; ++j)
                    acc[i][j] = __builtin_amdgcn_mfma_f32_16x16x32_bf16(a[i], b[j], acc[i][j], 0, 0, 0);
            __syncthreads();
        }
    }

#pragma unroll
    for (int j = 0; j < 8; ++j) {
        int col = wc + j * 16 + ln15;
        float bv = bias[col];
#pragma unroll
        for (int i = 0; i < 2; ++i) {
            int row0 = wr + i * 16 + quad * 4;
            f32x4_t c = acc[i][j];
#pragma unroll
            for (int p = 0; p < 4; ++p) smem[(row0 + p) * 260 + col] = bfr(c[p] + bv);
        }
    }
    __syncthreads();

    float4 g4 = *(const float4*)&g[l * 4];
    float4 be4 = *(const float4*)&be[l * 4];
    for (int rr = 0; rr < 16; ++rr) {
        int lrow = w * 16 + rr;
        int grow = bm + lrow;
        if (grow >= M) break;
        ushort4 ld = *(const ushort4*)(smem + lrow * 260 + l * 4);
        float v0 = bf2f(ld.x), v1 = bf2f(ld.y), v2 = bf2f(ld.z), v3 = bf2f(ld.w);
        float s = v0 + v1 + v2 + v3;
        float ss = v0 * v0 + v1 * v1 + v2 * v2 + v3 * v3;
#pragma unroll
        for (int m = 32; m >= 1; m >>= 1) {
            s += __shfl_xor(s, m);
            ss += __shfl_xor(ss, m);
        }
        float mean = s / 256.f;
        float var = ss / 256.f - mean * mean;
        float rs = rsqrtf(var + EPS);
        v0 = fmaxf((v0 - mean) * rs * g4.x + be4.x, 0.f);
        v1 = fmaxf((v1 - mean) * rs * g4.y + be4.y, 0.f);
        v2 = fmaxf((v2 - mean) * rs * g4.z + be4.z, 0.f);
        v3 = fmaxf((v3 - mean) * rs * g4.w + be4.w, 0.f);
        ((uint2*)out)[(long)grow * 64 + l] = make_uint2(bfpack(v0, v1), bfpack(v2, v3));
    }
}

// ---------------- L3 dual GEMM: ya = A@WTa, yb = A@WTb + bias ----------------
__global__ __launch_bounds__(256) void mfma_gemm_dual(const u16* __restrict__ A,
                                                      const u16* __restrict__ WTa,
                                                      const u16* __restrict__ WTb,
                                                      const float* __restrict__ biasb,
                                                      u16* __restrict__ outa,
                                                      u16* __restrict__ outb, int M, int K) {
    __shared__ u16 As[128 * 40];
    __shared__ u16 Ws[128 * 40];
    const u16* WT = blockIdx.y ? WTb : WTa;
    u16* out = blockIdx.y ? outb : outa;
    const float* bias = blockIdx.y ? biasb : nullptr;
    const int tid = threadIdx.x;
    const int bm = blockIdx.x * 128;
    const int l = tid & 63;
    const int w = tid >> 6;
    const int wr = (w & 1) * 64;
    const int wc = (w >> 1) * 64;
    const int ln15 = l & 15;
    const int quad = l >> 4;

    f32x4_t acc[4][4];
#pragma unroll
    for (int i = 0; i < 4; ++i)
#pragma unroll
        for (int j = 0; j < 4; ++j) acc[i][j] = (f32x4_t){0.f, 0.f, 0.f, 0.f};

    const int sr = tid >> 1;
    const int kh = (tid & 1) * 16;

    for (int k0 = 0; k0 < K; k0 += 32) {
        uint4 q0 = make_uint4(0, 0, 0, 0), q1 = make_uint4(0, 0, 0, 0);
        int gr = bm + sr;
        if (gr < M) {
            const u16* ap = A + (long)gr * K + k0 + kh;
            q0 = ((const uint4*)ap)[0];
            q1 = ((const uint4*)ap)[1];
        }
        *(uint4*)(As + sr * 40 + kh) = q0;
        *(uint4*)(As + sr * 40 + kh + 8) = q1;
        const u16* wp = WT + (long)sr * K + k0 + kh;
        *(uint4*)(Ws + sr * 40 + kh) = ((const uint4*)wp)[0];
        *(uint4*)(Ws + sr * 40 + kh + 8) = ((const uint4*)wp)[1];
        __syncthreads();

        bf16x8_t a[4], b[4];
#pragma unroll
        for (int i = 0; i < 4; ++i)
            a[i] = *(const bf16x8_t*)(As + (wr + i * 16 + ln15) * 40 + quad * 8);
#pragma unroll
        for (int j = 0; j < 4; ++j)
            b[j] = *(const bf16x8_t*)(Ws + (wc + j * 16 + ln15) * 40 + quad * 8);
#pragma unroll
        for (int i = 0; i < 4; ++i)
#pragma unroll
            for (int j = 0; j < 4; ++j)
                acc[i][j] = __builtin_amdgcn_mfma_f32_16x16x32_bf16(a[i], b[j], acc[i][j], 0, 0, 0);
        __syncthreads();
    }

#pragma unroll
    for (int j = 0; j < 4; ++j) {
        int col = wc + j * 16 + ln15;
        float bv = bias ? bias[col] : 0.f;
#pragma unroll
        for (int i = 0; i < 4; ++i) {
            int row0 = bm + wr + i * 16 + quad * 4;
            f32x4_t c = acc[i][j];
#pragma unroll
            for (int p = 0; p < 4; ++p) {
                int row = row0 + p;
                if (row < M) out[(long)row * 128 + col] = bfr(c[p] + bv);
            }
        }
    }
}

// ---------------- layer 4 small GEMM ----------------
__global__ __launch_bounds__(320) void gemm4_bf(const u16* __restrict__ x,
                                                const float* __restrict__ wm,
                                                const float* __restrict__ wrt,
                                                const float* __restrict__ b,
                                                u16* __restrict__ y, float* __restrict__ r,
                                                int M) {
    __shared__ float xs[16][132];
    __shared__ float ws[128][20];
    int tid = threadIdx.x;
    int m0 = blockIdx.x * 16;
    for (int idx = tid; idx < 16 * 128; idx += 320) {
        int rr = idx >> 7, kk = idx & 127;
        int gm = m0 + rr;
        xs[rr][kk] = (gm < M) ? bf2f(x[(long)gm * 128 + kk]) : 0.f;
    }
    for (int idx = tid; idx < 128 * 18; idx += 320) {
        int kk = idx / 18, cc = idx % 18;
        ws[kk][cc] = (cc < 9) ? wm[kk * 9 + cc] : wrt[kk * 9 + cc - 9];
    }
    __syncthreads();
    if (tid < 288) {
        int rr = tid / 18, cc = tid % 18;
        float acc = 0.f;
#pragma unroll 8
        for (int kk = 0; kk < 128; ++kk) acc += xs[rr][kk] * ws[kk][cc];
        int gm = m0 + rr;
        if (gm < M) {
            if (cc < 9) y[(long)gm * 9 + cc] = bfr(acc);
            else r[(long)gm * 9 + cc - 9] = acc + b[cc - 9];
        }
    }
}

static inline int cdiv(long a, long b) { return (int)((a + b - 1) / b); }

extern "C" void kernel_launch(void* const* d_in, const int* in_sizes, int n_in,
                              void* d_out, int out_size, void* d_ws, size_t ws_size,
                              hipStream_t stream) {
    const int N = in_sizes[0] / 128;
    const int E = in_sizes[1] / 2;

    const float* z = (const float*)d_in[0];
    const int* ei = (const int*)d_in[1];
    const int* src = ei;
    const int* dstp = ei + E;
    const float* wm1 = (const float*)d_in[2];
    const float* wr1 = (const float*)d_in[3];
    const float* b1 = (const float*)d_in[4];
    const float* g1 = (const float*)d_in[5];
    const float* be1 = (const float*)d_in[6];
    const float* wm2 = (const float*)d_in[7];
    const float* wr2 = (const float*)d_in[8];
    const float* b2 = (const float*)d_in[9];
    const float* g2 = (const float*)d_in[10];
    const float* be2 = (const float*)d_in[11];
    const float* wm3 = (const float*)d_in[12];
    const float* wr3 = (const float*)d_in[13];
    const float* b3 = (const float*)d_in[14];
    const float* g3 = (const float*)d_in[15];
    const float* be3 = (const float*)d_in[16];
    const float* wm4 = (const float*)d_in[17];
    const float* wr4 = (const float*)d_in[18];
    const float* b4 = (const float*)d_in[19];
    float* out = (float*)d_out;

    // ws layout:
    u16* aggh2 = (u16*)d_ws;                     // N*256
    u16* h1b = aggh2 + (size_t)N * 256;          // N*256
    u16* zb = h1b + (size_t)N * 256;             // N*128
    u16* agg1 = zb + (size_t)N * 128;            // N*128
    float* inv = (float*)(agg1 + (size_t)N * 128);
    int* deg = (int*)(inv + N);
    int* rowptr = deg + N + 4;
    int* cursor = rowptr + N + 4;
    int* partials = cursor + N + 4;
    int* eidx = partials + 256;
    u16* wt1m = (u16*)(eidx + E);
    u16* wt1r = wt1m + 256 * 128;
    u16* wt2m = wt1r + 256 * 128;
    u16* wt2r = wt2m + 256 * 256;
    u16* wt3m = wt2r + 256 * 256;
    u16* wt3r = wt3m + 128 * 256;

    // liveness-checked aliases:
    u16* y3b = agg1;
    u16* r3b = zb;
    u16* h3b = h1b;
    u16* y4 = aggh2;
    float* r4 = (float*)(aggh2 + (size_t)N * 16);

    const int nscan = cdiv(N, 1024);

    // ---- prep ----
    cast_bf16<<<cdiv((long)N * 32, 256), 256, 0, stream>>>(z, zb, N * 32);
    zero_f4<<<cdiv(N, 1024), 256, 0, stream>>>((float4*)deg, cdiv(N, 4));
    count_deg<<<cdiv(E, 256), 256, 0, stream>>>(dstp, deg, E);
    partial_sums<<<nscan, 256, 0, stream>>>(deg, partials, N);
    scan_partials<<<1, 256, 0, stream>>>(partials, nscan);
    write_rowptr<<<nscan, 256, 0, stream>>>(deg, partials, rowptr, cursor, inv, N, E);
    {
        const int P = 2;  // 3.2MB eidx window per pass <= 4MiB per-XCD L2
        int bs = cdiv(N, P);
        for (int b = 0; b < P; ++b)
            fill_csr_range<<<cdiv(E, 256), 256, 0, stream>>>(src, dstp, cursor, eidx, E,
                                                             b * bs, bs);
    }
    {
        WtJobs jobs;
        jobs.W[0] = wm1; jobs.WT[0] = wt1m; jobs.K[0] = 128; jobs.N[0] = 256;
        jobs.W[1] = wr1; jobs.WT[1] = wt1r; jobs.K[1] = 128; jobs.N[1] = 256;
        jobs.W[2] = wm2; jobs.WT[2] = wt2m; jobs.K[2] = 256; jobs.N[2] = 256;
        jobs.W[3] = wr2; jobs.WT[3] = wt2r; jobs.K[3] = 256; jobs.N[3] = 256;
        jobs.W[4] = wm3; jobs.WT[4] = wt3m; jobs.K[4] = 256; jobs.N[4] = 128;
        jobs.W[5] = wr3; jobs.WT[5] = wt3r; jobs.K[5] = 256; jobs.N[5] = 128;
        dim3 g(256, 6);
        transpose_cast6<<<g, 256, 0, stream>>>(jobs);
    }

    // ---- layer 1 ----
    gather_scale128<<<cdiv(N, 4), 256, 0, stream>>>(zb, rowptr, eidx, inv, agg1, N);
    mfma_gemm_wide_ln<<<cdiv(N, 64), 256, 0, stream>>>(agg1, zb, wt1m, wt1r, b1, g1, be1,
                                                       h1b, N, 128);

    // ---- layer 2 (in-place wide GEMM over agg buffer) ----
    gather_scale256<<<cdiv(N, 4), 256, 0, stream>>>(h1b, rowptr, eidx, inv, aggh2, N);
    mfma_gemm_wide_ln<<<cdiv(N, 64), 256, 0, stream>>>(aggh2, h1b, wt2m, wt2r, b2, g2, be2,
                                                       aggh2, N, 256);

    // ---- layer 3 ----
    {
        dim3 g(cdiv(N, 128), 2);
        mfma_gemm_dual<<<g, 256, 0, stream>>>(aggh2, wt3m, wt3r, b3, y3b, r3b, N, 256);
    }
    gather_add_ln_relu128<<<cdiv(N, 4), 256, 0, stream>>>(y3b, rowptr, eidx, inv, r3b, g3,
                                                          be3, h3b, N);

    // ---- layer 4 ----
    gemm4_bf<<<cdiv(N, 16), 320, 0, stream>>>(h3b, wm4, wr4, b4, y4, r4, N);
    gather9_final<<<cdiv((long)N * 16, 256), 256, 0, stream>>>(y4, rowptr, eidx, inv, r4, out, N);
}

// Round 12
// 835.822 us; speedup vs baseline: 1.0347x; 1.0103x over previous
//
#include <hip/hip_runtime.h>
#include <hip/hip_bf16.h>

// GraphSAGE decoder, 4 layers. CSR-gather aggregation, bf16 feature tables,
// bf16-MFMA GEMMs with fp32 accumulate, LN fused into GEMM epilogues.
// Measured config: BM=64 GEMM tile (R10's BM=128 regressed on occupancy),
// fill bucketed at P=4 (R9/R11 A/B: P=4=830us, P=2=844us), gathers at
// 16B/lane multi-edge (R9). y4 padded to stride-16 for aligned 9-col gathers.

#define EPS 1e-5f

typedef unsigned short u16;
typedef short bf16x8_t __attribute__((ext_vector_type(8)));
typedef float f32x4_t __attribute__((ext_vector_type(4)));

__device__ inline unsigned int bfpack(float a, float b) {
    unsigned int ua = __builtin_bit_cast(unsigned int, a);
    unsigned int ub = __builtin_bit_cast(unsigned int, b);
    ua += 0x7fffu + ((ua >> 16) & 1u);
    ub += 0x7fffu + ((ub >> 16) & 1u);
    return (ua >> 16) | (ub & 0xffff0000u);
}

__device__ inline u16 bfr(float a) {
    unsigned int u = __builtin_bit_cast(unsigned int, a);
    u += 0x7fffu + ((u >> 16) & 1u);
    return (u16)(u >> 16);
}

__device__ inline float bf2f(u16 v) {
    unsigned int u = ((unsigned int)v) << 16;
    return __builtin_bit_cast(float, u);
}

__device__ inline float bflo(unsigned int q) { return __builtin_bit_cast(float, q << 16); }
__device__ inline float bfhi(unsigned int q) { return __builtin_bit_cast(float, q & 0xffff0000u); }

#define ACC8(A, Q)                                         \
    A[0] += bflo(Q.x); A[1] += bfhi(Q.x);                  \
    A[2] += bflo(Q.y); A[3] += bfhi(Q.y);                  \
    A[4] += bflo(Q.z); A[5] += bfhi(Q.z);                  \
    A[6] += bflo(Q.w); A[7] += bfhi(Q.w);

// ---------------- zero fill ----------------
__global__ __launch_bounds__(256) void zero_f4(float4* __restrict__ p, int n4) {
    int i = blockIdx.x * 256 + threadIdx.x;
    if (i < n4) p[i] = make_float4(0.f, 0.f, 0.f, 0.f);
}

// ---------------- fp32 -> bf16 cast ----------------
__global__ __launch_bounds__(256) void cast_bf16(const float* __restrict__ x,
                                                 u16* __restrict__ y, int n4) {
    int i = blockIdx.x * 256 + threadIdx.x;
    if (i >= n4) return;
    float4 v = ((const float4*)x)[i];
    ((uint2*)y)[i] = make_uint2(bfpack(v.x, v.y), bfpack(v.z, v.w));
}

// ---------------- all 6 weight transposes in one launch ----------------
struct WtJobs {
    const float* W[6];
    u16* WT[6];
    int K[6], N[6];
};
__global__ __launch_bounds__(256) void transpose_cast6(WtJobs jobs) {
    int j = blockIdx.y;
    int idx = blockIdx.x * 256 + threadIdx.x;
    int K = jobs.K[j], Nn = jobs.N[j];
    if (idx >= K * Nn) return;
    int k = idx / Nn, n = idx - k * Nn;
    jobs.WT[j][(long)n * K + k] = bfr(jobs.W[j][idx]);
}

// ---------------- CSR build ----------------
__global__ __launch_bounds__(256) void count_deg(const int* __restrict__ dst,
                                                 int* __restrict__ deg, int E) {
    int e = blockIdx.x * 256 + threadIdx.x;
    if (e < E) atomicAdd(&deg[dst[e]], 1);
}

__global__ __launch_bounds__(256) void partial_sums(const int* __restrict__ deg,
                                                    int* __restrict__ partials, int N) {
    __shared__ int lds[4];
    int tid = threadIdx.x;
    int base = blockIdx.x * 1024 + tid * 4;
    int s = 0;
    if (base + 3 < N) {
        int4 v = *(const int4*)(deg + base);
        s = v.x + v.y + v.z + v.w;
    } else {
        for (int i = 0; i < 4; ++i)
            if (base + i < N) s += deg[base + i];
    }
#pragma unroll
    for (int m = 32; m >= 1; m >>= 1) s += __shfl_xor(s, m);
    if ((tid & 63) == 0) lds[tid >> 6] = s;
    __syncthreads();
    if (tid == 0) partials[blockIdx.x] = lds[0] + lds[1] + lds[2] + lds[3];
}

__global__ __launch_bounds__(256) void scan_partials(int* __restrict__ partials, int nb) {
    __shared__ int lds[256];
    int tid = threadIdx.x;
    int v = (tid < nb) ? partials[tid] : 0;
    lds[tid] = v;
    __syncthreads();
    for (int off = 1; off < 256; off <<= 1) {
        int t = (tid >= off) ? lds[tid - off] : 0;
        __syncthreads();
        lds[tid] += t;
        __syncthreads();
    }
    if (tid < nb) partials[tid] = lds[tid] - v;
}

__global__ __launch_bounds__(256) void write_rowptr(const int* __restrict__ deg,
                                                    const int* __restrict__ partials,
                                                    int* __restrict__ rowptr,
                                                    int* __restrict__ cursor,
                                                    float* __restrict__ inv, int N, int E) {
    __shared__ int lds[256];
    int tid = threadIdx.x;
    int base = blockIdx.x * 1024 + tid * 4;
    int d[4];
    int s = 0;
#pragma unroll
    for (int i = 0; i < 4; ++i) {
        d[i] = (base + i < N) ? deg[base + i] : 0;
        s += d[i];
    }
    lds[tid] = s;
    __syncthreads();
    for (int off = 1; off < 256; off <<= 1) {
        int t = (tid >= off) ? lds[tid - off] : 0;
        __syncthreads();
        lds[tid] += t;
        __syncthreads();
    }
    int run = partials[blockIdx.x] + lds[tid] - s;
#pragma unroll
    for (int i = 0; i < 4; ++i) {
        int idx = base + i;
        if (idx < N) {
            rowptr[idx] = run;
            cursor[idx] = run;
            inv[idx] = 1.0f / fmaxf((float)d[i], 1.0f);
            run += d[i];
        }
    }
    if (blockIdx.x == 0 && tid == 0) rowptr[N] = E;
}

__global__ __launch_bounds__(256) void fill_csr_range(const int* __restrict__ src,
                                                      const int* __restrict__ dst,
                                                      int* __restrict__ cursor,
                                                      int* __restrict__ eidx, int E,
                                                      int lo, int bs) {
    int e = blockIdx.x * 256 + threadIdx.x;
    if (e >= E) return;
    int d = dst[e];
    if ((unsigned)(d - lo) < (unsigned)bs) {
        int p = atomicAdd(&cursor[d], 1);
        eidx[p] = src[e];
    }
}

// ---------------- gathers: 16B/lane, multi-edge in flight ----------------
__global__ __launch_bounds__(256) void gather_scale256(const u16* __restrict__ x,
                                                       const int* __restrict__ rowptr,
                                                       const int* __restrict__ eidx,
                                                       const float* __restrict__ inv,
                                                       u16* __restrict__ agg, int N) {
    int wave = threadIdx.x >> 6;
    int lane = threadIdx.x & 63;
    int half = lane >> 5;
    int sub = lane & 31;
    int row = blockIdx.x * 4 + wave;
    if (row >= N) return;
    int beg = rowptr[row], end = rowptr[row + 1];
    float a[8] = {}, b[8] = {};
    int j = beg + half;
    for (; j + 2 < end; j += 4) {
        uint4 q0 = *(const uint4*)(x + (long)eidx[j] * 256 + sub * 8);
        uint4 q1 = *(const uint4*)(x + (long)eidx[j + 2] * 256 + sub * 8);
        ACC8(a, q0);
        ACC8(b, q1);
    }
    if (j < end) {
        uint4 q = *(const uint4*)(x + (long)eidx[j] * 256 + sub * 8);
        ACC8(a, q);
    }
#pragma unroll
    for (int i = 0; i < 8; ++i) {
        a[i] += b[i];
        a[i] += __shfl_xor(a[i], 32);
    }
    if (half == 0) {
        float s = inv[row];
        uint4 o;
        o.x = bfpack(a[0] * s, a[1] * s);
        o.y = bfpack(a[2] * s, a[3] * s);
        o.z = bfpack(a[4] * s, a[5] * s);
        o.w = bfpack(a[6] * s, a[7] * s);
        *(uint4*)(agg + (long)row * 256 + sub * 8) = o;
    }
}

__global__ __launch_bounds__(256) void gather_scale128(const u16* __restrict__ x,
                                                       const int* __restrict__ rowptr,
                                                       const int* __restrict__ eidx,
                                                       const float* __restrict__ inv,
                                                       u16* __restrict__ agg, int N) {
    int wave = threadIdx.x >> 6;
    int lane = threadIdx.x & 63;
    int quarter = lane >> 4;
    int sub = lane & 15;
    int row = blockIdx.x * 4 + wave;
    if (row >= N) return;
    int beg = rowptr[row], end = rowptr[row + 1];
    float a[8] = {}, b[8] = {};
    int j = beg + quarter;
    for (; j + 4 < end; j += 8) {
        uint4 q0 = *(const uint4*)(x + (long)eidx[j] * 128 + sub * 8);
        uint4 q1 = *(const uint4*)(x + (long)eidx[j + 4] * 128 + sub * 8);
        ACC8(a, q0);
        ACC8(b, q1);
    }
    if (j < end) {
        uint4 q = *(const uint4*)(x + (long)eidx[j] * 128 + sub * 8);
        ACC8(a, q);
    }
#pragma unroll
    for (int i = 0; i < 8; ++i) {
        a[i] += b[i];
        a[i] += __shfl_xor(a[i], 16);
        a[i] += __shfl_xor(a[i], 32);
    }
    if (quarter == 0) {
        float s = inv[row];
        uint4 o;
        o.x = bfpack(a[0] * s, a[1] * s);
        o.y = bfpack(a[2] * s, a[3] * s);
        o.z = bfpack(a[4] * s, a[5] * s);
        o.w = bfpack(a[6] * s, a[7] * s);
        *(uint4*)(agg + (long)row * 128 + sub * 8) = o;
    }
}

// L3 fused: h3 = relu(LN(gather_mean(y3) + r3)), D=128.
__global__ __launch_bounds__(256) void gather_add_ln_relu128(const u16* __restrict__ y,
                                                             const int* __restrict__ rowptr,
                                                             const int* __restrict__ eidx,
                                                             const float* __restrict__ inv,
                                                             const u16* __restrict__ r,
                                                             const float* __restrict__ g,
                                                             const float* __restrict__ be,
                                                             u16* __restrict__ out, int N) {
    int wave = threadIdx.x >> 6;
    int lane = threadIdx.x & 63;
    int quarter = lane >> 4;
    int sub = lane & 15;
    int row = blockIdx.x * 4 + wave;
    if (row >= N) return;
    int beg = rowptr[row], end = rowptr[row + 1];
    float a[8] = {}, b[8] = {};
    int j = beg + quarter;
    for (; j + 4 < end; j += 8) {
        uint4 q0 = *(const uint4*)(y + (long)eidx[j] * 128 + sub * 8);
        uint4 q1 = *(const uint4*)(y + (long)eidx[j + 4] * 128 + sub * 8);
        ACC8(a, q0);
        ACC8(b, q1);
    }
    if (j < end) {
        uint4 q = *(const uint4*)(y + (long)eidx[j] * 128 + sub * 8);
        ACC8(a, q);
    }
#pragma unroll
    for (int i = 0; i < 8; ++i) {
        a[i] += b[i];
        a[i] += __shfl_xor(a[i], 16);
        a[i] += __shfl_xor(a[i], 32);
    }
    float iv = inv[row];
    uint4 rr = *(const uint4*)(r + (long)row * 128 + sub * 8);
    float v[8];
    v[0] = a[0] * iv + bflo(rr.x); v[1] = a[1] * iv + bfhi(rr.x);
    v[2] = a[2] * iv + bflo(rr.y); v[3] = a[3] * iv + bfhi(rr.y);
    v[4] = a[4] * iv + bflo(rr.z); v[5] = a[5] * iv + bfhi(rr.z);
    v[6] = a[6] * iv + bflo(rr.w); v[7] = a[7] * iv + bfhi(rr.w);
    float s = 0.f, ss = 0.f;
#pragma unroll
    for (int i = 0; i < 8; ++i) { s += v[i]; ss += v[i] * v[i]; }
#pragma unroll
    for (int m = 8; m >= 1; m >>= 1) {
        s += __shfl_xor(s, m);
        ss += __shfl_xor(ss, m);
    }
    float mean = s / 128.f;
    float var = ss / 128.f - mean * mean;
    float rs = rsqrtf(var + EPS);
    if (quarter == 0) {
        int col = sub * 8;
        float4 g0 = *(const float4*)&g[col];
        float4 g1 = *(const float4*)&g[col + 4];
        float4 e0 = *(const float4*)&be[col];
        float4 e1 = *(const float4*)&be[col + 4];
        float o0 = fmaxf((v[0] - mean) * rs * g0.x + e0.x, 0.f);
        float o1 = fmaxf((v[1] - mean) * rs * g0.y + e0.y, 0.f);
        float o2 = fmaxf((v[2] - mean) * rs * g0.z + e0.z, 0.f);
        float o3 = fmaxf((v[3] - mean) * rs * g0.w + e0.w, 0.f);
        float o4 = fmaxf((v[4] - mean) * rs * g1.x + e1.x, 0.f);
        float o5 = fmaxf((v[5] - mean) * rs * g1.y + e1.y, 0.f);
        float o6 = fmaxf((v[6] - mean) * rs * g1.z + e1.z, 0.f);
        float o7 = fmaxf((v[7] - mean) * rs * g1.w + e1.w, 0.f);
        uint4 o;
        o.x = bfpack(o0, o1);
        o.y = bfpack(o2, o3);
        o.z = bfpack(o4, o5);
        o.w = bfpack(o6, o7);
        *(uint4*)(out + (long)row * 128 + sub * 8) = o;
    }
}

// final: out = gather_sum(y)*inv + r. y bf16 padded to row stride 16 (32B rows).
__global__ __launch_bounds__(256) void gather9_final(const u16* __restrict__ y,
                                                     const int* __restrict__ rowptr,
                                                     const int* __restrict__ eidx,
                                                     const float* __restrict__ inv,
                                                     const float* __restrict__ r,
                                                     float* __restrict__ out, int N) {
    int idx = blockIdx.x * 256 + threadIdx.x;
    int row = idx >> 4;
    int c = idx & 15;
    if (row >= N || c >= 9) return;
    int beg = rowptr[row], end = rowptr[row + 1];
    float a = 0.f;
    for (int j = beg; j < end; ++j) a += bf2f(y[((long)eidx[j] << 4) + c]);
    out[(long)row * 9 + c] = a * inv[row] + r[(long)row * 9 + c];
}

// ---------------- wide MFMA GEMM + fused bias+LN+ReLU epilogue ----------------
// out = relu(LN(A1@W1 + A2@W2 + bias))*g + be. BM=64, BN=256(=Dout), BK=32.
// out MAY alias A1 (each block owns rows [bm,bm+64) end-to-end).
__global__ __launch_bounds__(256) void mfma_gemm_wide_ln(const u16* A1,
                                                         const u16* __restrict__ A2,
                                                         const u16* __restrict__ WT1,
                                                         const u16* __restrict__ WT2,
                                                         const float* __restrict__ bias,
                                                         const float* __restrict__ g,
                                                         const float* __restrict__ be,
                                                         u16* out, int M, int K) {
    __shared__ __align__(16) u16 smem[64 * 260];
    u16* As = smem;
    u16* Ws = smem + 64 * 40;
    const int tid = threadIdx.x;
    const int bm = blockIdx.x * 64;
    const int l = tid & 63;
    const int w = tid >> 6;
    const int wr = (w & 1) * 32;
    const int wc = (w >> 1) * 128;
    const int ln15 = l & 15;
    const int quad = l >> 4;

    f32x4_t acc[2][8];
#pragma unroll
    for (int i = 0; i < 2; ++i)
#pragma unroll
        for (int j = 0; j < 8; ++j) acc[i][j] = (f32x4_t){0.f, 0.f, 0.f, 0.f};

    const int ar = tid >> 2;
    const int akh = (tid & 3) * 8;

    for (int pass = 0; pass < 2; ++pass) {
        const u16* A = pass ? A2 : A1;
        const u16* WT = pass ? WT2 : WT1;
        for (int k0 = 0; k0 < K; k0 += 32) {
            uint4 q0 = make_uint4(0, 0, 0, 0);
            int gr = bm + ar;
            if (gr < M) q0 = *(const uint4*)(A + (long)gr * K + k0 + akh);
            *(uint4*)(As + ar * 40 + akh) = q0;
            const u16* wp = WT + (long)tid * K + k0;
            *(uint4*)(Ws + tid * 40 + 0) = ((const uint4*)wp)[0];
            *(uint4*)(Ws + tid * 40 + 8) = ((const uint4*)wp)[1];
            *(uint4*)(Ws + tid * 40 + 16) = ((const uint4*)wp)[2];
            *(uint4*)(Ws + tid * 40 + 24) = ((const uint4*)wp)[3];
            __syncthreads();

            bf16x8_t a[2], b[8];
#pragma unroll
            for (int i = 0; i < 2; ++i)
                a[i] = *(const bf16x8_t*)(As + (wr + i * 16 + ln15) * 40 + quad * 8);
#pragma unroll
            for (int j = 0; j < 8; ++j)
                b[j] = *(const bf16x8_t*)(Ws + (wc + j * 16 + ln15) * 40 + quad * 8);
#pragma unroll
            for (int i = 0; i < 2; ++i)
#pragma unroll
                for (int j = 0; j < 8; ++j)
                    acc[i][j] = __builtin_amdgcn_mfma_f32_16x16x32_bf16(a[i], b[j], acc[i][j], 0, 0, 0);
            __syncthreads();
        }
    }

#pragma unroll
    for (int j = 0; j < 8; ++j) {
        int col = wc + j * 16 + ln15;
        float bv = bias[col];
#pragma unroll
        for (int i = 0; i < 2; ++i) {
            int row0 = wr + i * 16 + quad * 4;
            f32x4_t c = acc[i][j];
#pragma unroll
            for (int p = 0; p < 4; ++p) smem[(row0 + p) * 260 + col] = bfr(c[p] + bv);
        }
    }
    __syncthreads();

    float4 g4 = *(const float4*)&g[l * 4];
    float4 be4 = *(const float4*)&be[l * 4];
    for (int rr = 0; rr < 16; ++rr) {
        int lrow = w * 16 + rr;
        int grow = bm + lrow;
        if (grow >= M) break;
        ushort4 ld = *(const ushort4*)(smem + lrow * 260 + l * 4);
        float v0 = bf2f(ld.x), v1 = bf2f(ld.y), v2 = bf2f(ld.z), v3 = bf2f(ld.w);
        float s = v0 + v1 + v2 + v3;
        float ss = v0 * v0 + v1 * v1 + v2 * v2 + v3 * v3;
#pragma unroll
        for (int m = 32; m >= 1; m >>= 1) {
            s += __shfl_xor(s, m);
            ss += __shfl_xor(ss, m);
        }
        float mean = s / 256.f;
        float var = ss / 256.f - mean * mean;
        float rs = rsqrtf(var + EPS);
        v0 = fmaxf((v0 - mean) * rs * g4.x + be4.x, 0.f);
        v1 = fmaxf((v1 - mean) * rs * g4.y + be4.y, 0.f);
        v2 = fmaxf((v2 - mean) * rs * g4.z + be4.z, 0.f);
        v3 = fmaxf((v3 - mean) * rs * g4.w + be4.w, 0.f);
        ((uint2*)out)[(long)grow * 64 + l] = make_uint2(bfpack(v0, v1), bfpack(v2, v3));
    }
}

// ---------------- L3 dual GEMM: ya = A@WTa, yb = A@WTb + bias ----------------
__global__ __launch_bounds__(256) void mfma_gemm_dual(const u16* __restrict__ A,
                                                      const u16* __restrict__ WTa,
                                                      const u16* __restrict__ WTb,
                                                      const float* __restrict__ biasb,
                                                      u16* __restrict__ outa,
                                                      u16* __restrict__ outb, int M, int K) {
    __shared__ u16 As[128 * 40];
    __shared__ u16 Ws[128 * 40];
    const u16* WT = blockIdx.y ? WTb : WTa;
    u16* out = blockIdx.y ? outb : outa;
    const float* bias = blockIdx.y ? biasb : nullptr;
    const int tid = threadIdx.x;
    const int bm = blockIdx.x * 128;
    const int l = tid & 63;
    const int w = tid >> 6;
    const int wr = (w & 1) * 64;
    const int wc = (w >> 1) * 64;
    const int ln15 = l & 15;
    const int quad = l >> 4;

    f32x4_t acc[4][4];
#pragma unroll
    for (int i = 0; i < 4; ++i)
#pragma unroll
        for (int j = 0; j < 4; ++j) acc[i][j] = (f32x4_t){0.f, 0.f, 0.f, 0.f};

    const int sr = tid >> 1;
    const int kh = (tid & 1) * 16;

    for (int k0 = 0; k0 < K; k0 += 32) {
        uint4 q0 = make_uint4(0, 0, 0, 0), q1 = make_uint4(0, 0, 0, 0);
        int gr = bm + sr;
        if (gr < M) {
            const u16* ap = A + (long)gr * K + k0 + kh;
            q0 = ((const uint4*)ap)[0];
            q1 = ((const uint4*)ap)[1];
        }
        *(uint4*)(As + sr * 40 + kh) = q0;
        *(uint4*)(As + sr * 40 + kh + 8) = q1;
        const u16* wp = WT + (long)sr * K + k0 + kh;
        *(uint4*)(Ws + sr * 40 + kh) = ((const uint4*)wp)[0];
        *(uint4*)(Ws + sr * 40 + kh + 8) = ((const uint4*)wp)[1];
        __syncthreads();

        bf16x8_t a[4], b[4];
#pragma unroll
        for (int i = 0; i < 4; ++i)
            a[i] = *(const bf16x8_t*)(As + (wr + i * 16 + ln15) * 40 + quad * 8);
#pragma unroll
        for (int j = 0; j < 4; ++j)
            b[j] = *(const bf16x8_t*)(Ws + (wc + j * 16 + ln15) * 40 + quad * 8);
#pragma unroll
        for (int i = 0; i < 4; ++i)
#pragma unroll
            for (int j = 0; j < 4; ++j)
                acc[i][j] = __builtin_amdgcn_mfma_f32_16x16x32_bf16(a[i], b[j], acc[i][j], 0, 0, 0);
        __syncthreads();
    }

#pragma unroll
    for (int j = 0; j < 4; ++j) {
        int col = wc + j * 16 + ln15;
        float bv = bias ? bias[col] : 0.f;
#pragma unroll
        for (int i = 0; i < 4; ++i) {
            int row0 = bm + wr + i * 16 + quad * 4;
            f32x4_t c = acc[i][j];
#pragma unroll
            for (int p = 0; p < 4; ++p) {
                int row = row0 + p;
                if (row < M) out[(long)row * 128 + col] = bfr(c[p] + bv);
            }
        }
    }
}

// ---------------- layer 4 small GEMM: y (stride 16), r (stride 9 fp32) ----------
__global__ __launch_bounds__(320) void gemm4_bf(const u16* __restrict__ x,
                                                const float* __restrict__ wm,
                                                const float* __restrict__ wrt,
                                                const float* __restrict__ b,
                                                u16* __restrict__ y, float* __restrict__ r,
                                                int M) {
    __shared__ float xs[16][132];
    __shared__ float ws[128][20];
    int tid = threadIdx.x;
    int m0 = blockIdx.x * 16;
    for (int idx = tid; idx < 16 * 128; idx += 320) {
        int rr = idx >> 7, kk = idx & 127;
        int gm = m0 + rr;
        xs[rr][kk] = (gm < M) ? bf2f(x[(long)gm * 128 + kk]) : 0.f;
    }
    for (int idx = tid; idx < 128 * 18; idx += 320) {
        int kk = idx / 18, cc = idx % 18;
        ws[kk][cc] = (cc < 9) ? wm[kk * 9 + cc] : wrt[kk * 9 + cc - 9];
    }
    __syncthreads();
    if (tid < 288) {
        int rr = tid / 18, cc = tid % 18;
        float acc = 0.f;
#pragma unroll 8
        for (int kk = 0; kk < 128; ++kk) acc += xs[rr][kk] * ws[kk][cc];
        int gm = m0 + rr;
        if (gm < M) {
            if (cc < 9) y[((long)gm << 4) + cc] = bfr(acc);
            else r[(long)gm * 9 + cc - 9] = acc + b[cc - 9];
        }
    }
}

static inline int cdiv(long a, long b) { return (int)((a + b - 1) / b); }

extern "C" void kernel_launch(void* const* d_in, const int* in_sizes, int n_in,
                              void* d_out, int out_size, void* d_ws, size_t ws_size,
                              hipStream_t stream) {
    const int N = in_sizes[0] / 128;
    const int E = in_sizes[1] / 2;

    const float* z = (const float*)d_in[0];
    const int* ei = (const int*)d_in[1];
    const int* src = ei;
    const int* dstp = ei + E;
    const float* wm1 = (const float*)d_in[2];
    const float* wr1 = (const float*)d_in[3];
    const float* b1 = (const float*)d_in[4];
    const float* g1 = (const float*)d_in[5];
    const float* be1 = (const float*)d_in[6];
    const float* wm2 = (const float*)d_in[7];
    const float* wr2 = (const float*)d_in[8];
    const float* b2 = (const float*)d_in[9];
    const float* g2 = (const float*)d_in[10];
    const float* be2 = (const float*)d_in[11];
    const float* wm3 = (const float*)d_in[12];
    const float* wr3 = (const float*)d_in[13];
    const float* b3 = (const float*)d_in[14];
    const float* g3 = (const float*)d_in[15];
    const float* be3 = (const float*)d_in[16];
    const float* wm4 = (const float*)d_in[17];
    const float* wr4 = (const float*)d_in[18];
    const float* b4 = (const float*)d_in[19];
    float* out = (float*)d_out;

    // ws layout:
    u16* aggh2 = (u16*)d_ws;                     // N*256
    u16* h1b = aggh2 + (size_t)N * 256;          // N*256
    u16* zb = h1b + (size_t)N * 256;             // N*128
    u16* agg1 = zb + (size_t)N * 128;            // N*128
    float* inv = (float*)(agg1 + (size_t)N * 128);
    int* deg = (int*)(inv + N);
    int* rowptr = deg + N + 4;
    int* cursor = rowptr + N + 4;
    int* partials = cursor + N + 4;
    int* eidx = partials + 256;
    u16* wt1m = (u16*)(eidx + E);
    u16* wt1r = wt1m + 256 * 128;
    u16* wt2m = wt1r + 256 * 128;
    u16* wt2r = wt2m + 256 * 256;
    u16* wt3m = wt2r + 256 * 256;
    u16* wt3r = wt3m + 128 * 256;

    // liveness-checked aliases:
    u16* y3b = agg1;
    u16* r3b = zb;
    u16* h3b = h1b;
    u16* y4 = aggh2;                               // N*16 u16 (padded stride 16)
    float* r4 = (float*)(aggh2 + (size_t)N * 16);  // N*9 fp32, 16B-aligned

    const int nscan = cdiv(N, 1024);

    // ---- prep ----
    cast_bf16<<<cdiv((long)N * 32, 256), 256, 0, stream>>>(z, zb, N * 32);
    zero_f4<<<cdiv(N, 1024), 256, 0, stream>>>((float4*)deg, cdiv(N, 4));
    count_deg<<<cdiv(E, 256), 256, 0, stream>>>(dstp, deg, E);
    partial_sums<<<nscan, 256, 0, stream>>>(deg, partials, N);
    scan_partials<<<1, 256, 0, stream>>>(partials, nscan);
    write_rowptr<<<nscan, 256, 0, stream>>>(deg, partials, rowptr, cursor, inv, N, E);
    {
        const int P = 4;  // measured best (R9/R11 A/B: P=4 beats P=2 and P=8)
        int bs = cdiv(N, P);
        for (int b = 0; b < P; ++b)
            fill_csr_range<<<cdiv(E, 256), 256, 0, stream>>>(src, dstp, cursor, eidx, E,
                                                             b * bs, bs);
    }
    {
        WtJobs jobs;
        jobs.W[0] = wm1; jobs.WT[0] = wt1m; jobs.K[0] = 128; jobs.N[0] = 256;
        jobs.W[1] = wr1; jobs.WT[1] = wt1r; jobs.K[1] = 128; jobs.N[1] = 256;
        jobs.W[2] = wm2; jobs.WT[2] = wt2m; jobs.K[2] = 256; jobs.N[2] = 256;
        jobs.W[3] = wr2; jobs.WT[3] = wt2r; jobs.K[3] = 256; jobs.N[3] = 256;
        jobs.W[4] = wm3; jobs.WT[4] = wt3m; jobs.K[4] = 256; jobs.N[4] = 128;
        jobs.W[5] = wr3; jobs.WT[5] = wt3r; jobs.K[5] = 256; jobs.N[5] = 128;
        dim3 g(256, 6);
        transpose_cast6<<<g, 256, 0, stream>>>(jobs);
    }

    // ---- layer 1 ----
    gather_scale128<<<cdiv(N, 4), 256, 0, stream>>>(zb, rowptr, eidx, inv, agg1, N);
    mfma_gemm_wide_ln<<<cdiv(N, 64), 256, 0, stream>>>(agg1, zb, wt1m, wt1r, b1, g1, be1,
                                                       h1b, N, 128);

    // ---- layer 2 (in-place wide GEMM over agg buffer) ----
    gather_scale256<<<cdiv(N, 4), 256, 0, stream>>>(h1b, rowptr, eidx, inv, aggh2, N);
    mfma_gemm_wide_ln<<<cdiv(N, 64), 256, 0, stream>>>(aggh2, h1b, wt2m, wt2r, b2, g2, be2,
                                                       aggh2, N, 256);

    // ---- layer 3 ----
    {
        dim3 g(cdiv(N, 128), 2);
        mfma_gemm_dual<<<g, 256, 0, stream>>>(aggh2, wt3m, wt3r, b3, y3b, r3b, N, 256);
    }
    gather_add_ln_relu128<<<cdiv(N, 4), 256, 0, stream>>>(y3b, rowptr, eidx, inv, r3b, g3,
                                                          be3, h3b, N);

    // ---- layer 4 ----
    gemm4_bf<<<cdiv(N, 16), 320, 0, stream>>>(h3b, wm4, wr4, b4, y4, r4, N);
    gather9_final<<<cdiv((long)N * 16, 256), 256, 0, stream>>>(y4, rowptr, eidx, inv, r4, out, N);
}